// Round 17
// baseline (497.079 us; speedup 1.0000x reference)
//
#include <hip/hip_runtime.h>
#include <cstdint>
#include <cstddef>

#define DI __device__ __forceinline__

namespace pk {

constexpr int NB1 = 65536;      // stage-1 nodes (B*N)
constexpr int NE  = 1048576;    // edges (B*N*DEG)
constexpr int BG  = 8;          // graphs
constexpr int NPG1 = 8192;      // nodes per graph, stage 1
constexpr int EPG1 = NE/BG;     // edges per graph, stage 1 (131072)
constexpr int KP1 = 2458;       // top-k 1
constexpr int KP2 = 738;        // top-k 2
constexpr int NN2 = BG*KP1;     // 19664
constexpr int NN3 = BG*KP2;     // 5904
constexpr int REG2 = 16384;     // per-graph edge region after pool1 (exp 11.8K±0.1K)
constexpr int REG3 = 4096;      // per-graph edge region after pool2 (exp ~1.1K)
constexpr int CAP2 = BG*REG2;
constexpr int CAP3 = BG*REG3;

DI float lrelu(float x){ return x > 0.f ? x : 0.2f*x; }
DI float eluf(float x){ return x > 0.f ? x : expf(x) - 1.f; }

// XCD-affinity swizzle (heuristic only).
DI int swz_block(){
  int nb = gridDim.x, b = blockIdx.x;
  if((nb & 7) == 0) return (b & 7)*(nb >> 3) + (b >> 3);
  return b;
}

// ---- stage-1 projection: xp = pos @ W1 (K=3), plus attention logits per head
__global__ __launch_bounds__(256) void k_xp1(
    const float* __restrict__ pos, const float* __restrict__ W,
    const float* __restrict__ as_, const float* __restrict__ ad_,
    float* __restrict__ xp, float* __restrict__ als, float* __restrict__ ald){
  int i = blockIdx.x*256 + threadIdx.x;
  if(i >= NB1) return;
  float p0=pos[3*i], p1=pos[3*i+1], p2=pos[3*i+2];
  float row[32];
#pragma unroll
  for(int c=0;c<32;c++) row[c] = p0*W[c] + p1*W[32+c] + p2*W[64+c];
  float s0=0.f,d0=0.f,s1=0.f,d1=0.f;
#pragma unroll
  for(int f=0;f<16;f++){
    s0 += row[f]*as_[f];        d0 += row[f]*ad_[f];
    s1 += row[16+f]*as_[16+f];  d1 += row[16+f]*ad_[16+f];
  }
  float4* o = reinterpret_cast<float4*>(xp + (size_t)i*32);
#pragma unroll
  for(int q=0;q<8;q++) o[q] = make_float4(row[4*q],row[4*q+1],row[4*q+2],row[4*q+3]);
  als[2*i]=s0; als[2*i+1]=s1; ald[2*i]=d0; ald[2*i+1]=d1;
}

// ---- stage-1 dst-tiled CSR build
__global__ __launch_bounds__(1024) void k_tile_count(
    const int* __restrict__ de, int* __restrict__ cnt){
  __shared__ int h[256];
  int tid = threadIdx.x;
  int g = blockIdx.x & 7, t = blockIdx.x >> 3;
  int lo = g*NPG1 + t*256;
  if(tid < 256) h[tid] = 0;
  __syncthreads();
  const int4* de4 = (const int4*)(de + g*EPG1);   // 32768 int4s per graph
  for(int it=0; it<4; it++){
    int4 buf[8];
#pragma unroll
    for(int j=0;j<8;j++) buf[j] = de4[(it*8+j)*1024 + tid];
#pragma unroll
    for(int j=0;j<8;j++){
      int4 b = buf[j];
      int d0=b.x-lo, d1=b.y-lo, d2=b.z-lo, d3=b.w-lo;
      if((unsigned)d0<256u) atomicAdd(&h[d0],1);
      if((unsigned)d1<256u) atomicAdd(&h[d1],1);
      if((unsigned)d2<256u) atomicAdd(&h[d2],1);
      if((unsigned)d3<256u) atomicAdd(&h[d3],1);
    }
  }
  __syncthreads();
  if(tid < 256) cnt[lo + tid] = h[tid];
}

__global__ __launch_bounds__(1024) void k_tile_scatter(
    const int* __restrict__ se, const int* __restrict__ de,
    const int* __restrict__ rowptr, int* __restrict__ eo){
  __shared__ int cur[256];
  int tid = threadIdx.x;
  int g = blockIdx.x & 7, t = blockIdx.x >> 3;
  int lo = g*NPG1 + t*256;
  if(tid < 256) cur[tid] = rowptr[lo + tid];
  __syncthreads();
  const int4* de4 = (const int4*)(de + g*EPG1);
  const int4* se4 = (const int4*)(se + g*EPG1);
  for(int it=0; it<4; it++){
    int4 bd[8], bs[8];
#pragma unroll
    for(int j=0;j<8;j++){
      int idx = (it*8+j)*1024 + tid;
      bd[j] = de4[idx]; bs[j] = se4[idx];
    }
#pragma unroll
    for(int j=0;j<8;j++){
      int4 d = bd[j], s = bs[j];
      int d0=d.x-lo; if((unsigned)d0<256u){ int p=atomicAdd(&cur[d0],1); eo[p]=s.x; }
      int d1=d.y-lo; if((unsigned)d1<256u){ int p=atomicAdd(&cur[d1],1); eo[p]=s.y; }
      int d2=d.z-lo; if((unsigned)d2<256u){ int p=atomicAdd(&cur[d2],1); eo[p]=s.z; }
      int d3=d.w-lo; if((unsigned)d3<256u){ int p=atomicAdd(&cur[d3],1); eo[p]=s.w; }
    }
  }
}

// per-graph-region atomic scatter (stages 2/3)
__global__ __launch_bounds__(256) void k_scatter_r(
    const int* __restrict__ se, const int* __restrict__ de,
    const int* __restrict__ gcnt, int reg,
    int* __restrict__ cursor, int* __restrict__ eo){
  int i = swz_block()*256 + threadIdx.x;
  int g = i / reg, loc = i % reg;
  if(loc < gcnt[g]){
    int p = atomicAdd(&cursor[de[i]], 1);
    eo[p] = se[i];
  }
}

// stream compaction into PER-GRAPH regions, fused degree count.
__global__ __launch_bounds__(256) void k_edge_compact(
    const int* __restrict__ se, const int* __restrict__ de,
    const int* __restrict__ gcnt_in, int fixed_in, int bpg, int reg_in,
    const int* __restrict__ newid, int* __restrict__ gcnt_out,
    int* __restrict__ ons, int* __restrict__ ond, int reg_out,
    int* __restrict__ cnt){
  __shared__ int s_a[4096];
  __shared__ int s_b[4096];
  __shared__ int run, tbase;
  int tid = threadIdx.x;
  if(tid == 0) run = 0;
  __syncthreads();
  int blk = swz_block();
  int g = blk / bpg, t = blk % bpg;
  int mg = gcnt_in ? gcnt_in[g] : fixed_in;
  if(mg > reg_in) mg = reg_in;
  int base_l = t*4096;
  if(base_l < mg){
    const int* deb = de + (size_t)g*reg_in + base_l;
    const int* seb = se + (size_t)g*reg_in + base_l;
    const int4* de4 = (const int4*)deb;
    const int4* se4 = (const int4*)seb;
    int4 BD[4], BS[4];
#pragma unroll
    for(int j=0;j<4;j++){ BD[j]=de4[j*256+tid]; BS[j]=se4[j*256+tid]; }
#pragma unroll
    for(int j=0;j<4;j++){
      int eb = base_l + (j*256+tid)*4;
      int dd[4]={BD[j].x,BD[j].y,BD[j].z,BD[j].w};
      int ss[4]={BS[j].x,BS[j].y,BS[j].z,BS[j].w};
#pragma unroll
      for(int q=0;q<4;q++){
        if(eb+q < mg){
          int a = newid[ss[q]], b = newid[dd[q]];
          if(a>=0 && b>=0){
            int p = atomicAdd(&run, 1);
            s_a[p]=a; s_b[p]=b;
            atomicAdd(&cnt[b], 1);
          }
        }
      }
    }
  }
  __syncthreads();
  int ns = run;
  if(tid==0) tbase = ns ? atomicAdd(&gcnt_out[g], ns) : 0;
  __syncthreads();
  int tb = tbase;
  for(int j=tid; j<ns; j+=256){
    int s2 = tb + j;
    if(s2 < reg_out){ ons[(size_t)g*reg_out+s2]=s_a[j]; ond[(size_t)g*reg_out+s2]=s_b[j]; }
  }
}

// per-graph single-block exclusive scan (one dispatch; graphs independent)
__global__ __launch_bounds__(1024) void k_scan_g(
    const int* __restrict__ cnt, int R, int estride,
    int* __restrict__ rowptr, int* __restrict__ cursor){
  __shared__ int wsum[16];
  int g = blockIdx.x;
  int tid = threadIdx.x, lane = tid & 63, w = tid >> 6;
  int PER = (R + 1023) >> 10;
  int base = g*R;
  int i0 = tid*PER;
  int v[8]; int s = 0;
  for(int j=0;j<PER;j++){ int i=i0+j; int x=(i<R)?cnt[base+i]:0; v[j]=s; s+=x; }
  int inc = s;
  for(int o=1;o<64;o<<=1){ int t=__shfl_up(inc,o,64); if(lane>=o) inc+=t; }
  if(lane==63) wsum[w]=inc;
  __syncthreads();
  int wb=0;
  for(int k=0;k<w;k++) wb+=wsum[k];
  int tb = g*estride + wb + inc - s;
  for(int j=0;j<PER;j++){
    int i=i0+j;
    if(i<R){
      int e=tb+v[j];
      rowptr[base+i]=e;
      if(cursor) cursor[base+i]=e;
    }
  }
}

// FUSED GAT: weights (lane-parallel into LDS) + softmax-normalized aggregate
// + FUSED inorm stats (block LDS channel reduce -> accum; replaces
// k_inorm_stats and its 24MB re-read of out1/2/3). Grids are exact multiples
// of NPB so no early-return hazard around the added __syncthreads.
template<int H,int F,int ECAP>
__global__ __launch_bounds__(256) void k_gat_fused(
    const float* __restrict__ xp, const float* __restrict__ als,
    const float* __restrict__ ald, const int* __restrict__ rowptr,
    const int* __restrict__ cnt, const int* __restrict__ esrc,
    const float* __restrict__ bias, float* __restrict__ out,
    float* __restrict__ accum, int RPG, int n){
  constexpr int C = H*F, C4 = C/4, NPB = 256/C4;
  __shared__ int rst[NPB];
  __shared__ int ecum[NPB+1];
  __shared__ float aldv[NPB*H];
  __shared__ float wselfs[NPB*H];
  __shared__ float dens[NPB*H];
  __shared__ float wexps[ECAP*H];
  __shared__ float ssum[C], ssq[C];
  int tid = threadIdx.x;
  int node0 = swz_block()*NPB;
  if(tid < NPB){
    int node = node0 + tid;
    rst[tid] = (node < n) ? rowptr[node] : 0;
  }
  if(tid < C){ ssum[tid]=0.f; ssq[tid]=0.f; }
  if(tid < 64){
    int d = (tid < NPB && node0+tid < n) ? cnt[node0+tid] : 0;
    int inc = d;
    for(int o=1;o<64;o<<=1){ int t2=__shfl_up(inc,o,64); if(tid>=o) inc+=t2; }
    if(tid < NPB) ecum[tid] = inc - d;
    if(tid == NPB-1) ecum[NPB] = inc;
  }
  if(tid < NPB*H){
    int node = node0 + tid/H, h = tid%H;
    float dv = 0.f, sw = 0.f;
    if(node < n){ dv = ald[node*H+h]; sw = expf(lrelu(als[node*H+h] + dv)); }
    aldv[tid]=dv; wselfs[tid]=sw; dens[tid]=sw;
  }
  __syncthreads();
  int totE = ecum[NPB];
  for(int s=tid; s<totE; s+=256){
    int lo=0, hi=NPB;
    while(hi-lo > 1){ int mid=(lo+hi)>>1; if(ecum[mid] <= s) lo=mid; else hi=mid; }
    int k = rst[lo] + (s - ecum[lo]);
    int srcn = esrc[k];
    if(H == 2){
      float2 a = ((const float2*)als)[srcn];
      float e0 = expf(lrelu(a.x + aldv[lo*2]));
      float e1 = expf(lrelu(a.y + aldv[lo*2+1]));
      if(s < ECAP){ wexps[s*2]=e0; wexps[s*2+1]=e1; }
      atomicAdd(&dens[lo*2], e0);
      atomicAdd(&dens[lo*2+1], e1);
    } else {
      float e0 = expf(lrelu(als[srcn] + aldv[lo]));
      if(s < ECAP) wexps[s]=e0;
      atomicAdd(&dens[lo], e0);
    }
  }
  __syncthreads();
  int nl = tid / C4, p = tid % C4;
  int node = node0 + nl;
  int hh = (4*p)/F;
  const float4* xp4 = (const float4*)xp;
  float4 r = make_float4(0.f,0.f,0.f,0.f);
  bool valid = node < n;
  if(valid){
    float4 xs = xp4[(size_t)node*C4 + p];
    float sw = wselfs[nl*H+hh];
    float ax=sw*xs.x, ay=sw*xs.y, az=sw*xs.z, aw_=sw*xs.w;
    int r0 = rst[nl], e0o = ecum[nl], deg = ecum[nl+1]-e0o;
    float dvh = aldv[nl*H+hh];
#pragma unroll 4
    for(int j=0;j<deg;j++){
      int s = e0o + j;
      int srcn = esrc[r0+j];
      float w = (s < ECAP) ? wexps[s*H+hh]
                           : expf(lrelu(als[srcn*H+hh] + dvh));
      float4 v = xp4[(size_t)srcn*C4 + p];
      ax+=w*v.x; ay+=w*v.y; az+=w*v.z; aw_+=w*v.w;
    }
    float inv = 1.f / dens[nl*H+hh];
    float4 bv = ((const float4*)bias)[p];
    r.x=ax*inv+bv.x; r.y=ay*inv+bv.y; r.z=az*inv+bv.z; r.w=aw_*inv+bv.w;
    ((float4*)out)[(size_t)node*C4 + p] = r;
  }
  // ---- fused inorm stats
  int g0 = node0 / RPG;
  bool straddle = ((node0 + NPB - 1) / RPG) != g0;
  if(valid){
    if(!straddle){
      atomicAdd(&ssum[4*p+0], r.x); atomicAdd(&ssq[4*p+0], r.x*r.x);
      atomicAdd(&ssum[4*p+1], r.y); atomicAdd(&ssq[4*p+1], r.y*r.y);
      atomicAdd(&ssum[4*p+2], r.z); atomicAdd(&ssq[4*p+2], r.z*r.z);
      atomicAdd(&ssum[4*p+3], r.w); atomicAdd(&ssq[4*p+3], r.w*r.w);
    } else {
      int g = node / RPG;
      atomicAdd(&accum[(g*C+4*p+0)*2], r.x); atomicAdd(&accum[(g*C+4*p+0)*2+1], r.x*r.x);
      atomicAdd(&accum[(g*C+4*p+1)*2], r.y); atomicAdd(&accum[(g*C+4*p+1)*2+1], r.y*r.y);
      atomicAdd(&accum[(g*C+4*p+2)*2], r.z); atomicAdd(&accum[(g*C+4*p+2)*2+1], r.z*r.z);
      atomicAdd(&accum[(g*C+4*p+3)*2], r.w); atomicAdd(&accum[(g*C+4*p+3)*2+1], r.w*r.w);
    }
  }
  __syncthreads();
  if(!straddle && tid < C){
    atomicAdd(&accum[(g0*C+tid)*2],   ssum[tid]);
    atomicAdd(&accum[(g0*C+tid)*2+1], ssq[tid]);
  }
}

// dense row-GEMM with fused POOL-GATHER input (X[oldid[row]]*scale[row]) and
// fused attention-logit epilogue.
template<int K,int CO,int NPG,int H>
__global__ __launch_bounds__(256) void k_gemm_al(
    const float* __restrict__ X, const int* __restrict__ oldid,
    const float* __restrict__ scale, const float* __restrict__ W,
    float* __restrict__ Y, const float* __restrict__ a_s,
    const float* __restrict__ a_d, float* __restrict__ als,
    float* __restrict__ ald, int n){
  constexpr int SUB = 256/CO;
  constexpr int NB = SUB*NPG;
  __shared__ float xs[NB][K];
  __shared__ float ps[4][NPG], pd[4][NPG];
  int tid = threadIdx.x;
  int c = tid % CO, sg = tid / CO;
  int n0 = blockIdx.x * NB;
  for(int idx=tid; idx<NB*K; idx+=256){
    int r = idx / K, k = idx % K;
    int row = n0 + r;
    float v = 0.f;
    if(row < n){
      int orow = oldid[row];
      v = X[(size_t)orow*K + k] * scale[row];
    }
    xs[r][k] = v;
  }
  __syncthreads();
  float acc[NPG];
#pragma unroll
  for(int q=0;q<NPG;q++) acc[q]=0.f;
  for(int k=0;k<K;k++){
    float wv = W[(size_t)k*CO + c];
#pragma unroll
    for(int q=0;q<NPG;q++) acc[q] += xs[sg*NPG+q][k]*wv;
  }
  float asc = a_s[c], adc = a_d[c];
  float vs[NPG], vd[NPG];
#pragma unroll
  for(int q=0;q<NPG;q++){
    int row = n0 + sg*NPG + q;
    if(row < n) Y[(size_t)row*CO + c] = acc[q];
    vs[q] = acc[q]*asc; vd[q] = acc[q]*adc;
  }
#pragma unroll
  for(int o=32;o>0;o>>=1){
#pragma unroll
    for(int q=0;q<NPG;q++){
      vs[q] += __shfl_down(vs[q], o, 64);
      vd[q] += __shfl_down(vd[q], o, 64);
    }
  }
  int lane = tid & 63, w = tid >> 6;
  if(H == 2){
    if(lane == 0){
      int sg_ = w >> 1, h = w & 1;
#pragma unroll
      for(int q=0;q<NPG;q++){
        int row = n0 + sg_*NPG + q;
        if(row < n){ als[row*2+h] = vs[q]; ald[row*2+h] = vd[q]; }
      }
    }
  } else {
    if(lane == 0){
#pragma unroll
      for(int q=0;q<NPG;q++){ ps[w][q]=vs[q]; pd[w][q]=vd[q]; }
    }
    __syncthreads();
    if(tid < NPG){
      float s=0.f, d=0.f;
      for(int ww=0;ww<4;ww++){ s+=ps[ww][tid]; d+=pd[ww][tid]; }
      int row = n0 + tid;
      if(row < n){ als[row]=s; ald[row]=d; }
    }
  }
}

// inorm normalize helper from accum stats
DI float inorm_of(const float* accum, int gc, float R, float x){
  float s = accum[gc*2], sq = accum[gc*2+1];
  float mu = s / R;
  float var = fmaxf(sq/R - mu*mu, 0.f);
  return eluf((x-mu)*rsqrtf(var+1e-5f));
}

// fused inorm-apply + ELU + pool score + orderable key (stages 1/2).
template<int C>
__global__ __launch_bounds__(256) void k_inorm_score(
    float* __restrict__ x, const float* __restrict__ accum,
    const float* __restrict__ p, int R, int total,
    float* __restrict__ score, unsigned* __restrict__ u){
  __shared__ float rvp[256], rpp[256];
  int tid = threadIdx.x;
  int i = blockIdx.x*256 + tid;
  int c = tid & (C-1);
  bool act = i < total;
  float v = 0.f, pv = 0.f;
  if(act){
    int g = i / (R*C);
    v = inorm_of(accum, g*C+c, (float)R, x[i]);
    x[i] = v;
    pv = p[c];
  }
  rvp[tid] = v*pv; rpp[tid] = pv*pv;
  __syncthreads();
#pragma unroll
  for(int s2=C/2; s2>0; s2>>=1){
    if(c < s2){ rvp[tid]+=rvp[tid+s2]; rpp[tid]+=rpp[tid+s2]; }
    __syncthreads();
  }
  if(act && c==0){
    float sv = tanhf(rvp[tid]*rsqrtf(rpp[tid]));
    int row = i / C;
    score[row] = sv;
    unsigned bts = __float_as_uint(sv);
    u[row] = (bts & 0x80000000u) ? ~bts : (bts | 0x80000000u);
  }
}

// MERGED top-k: radix select (exact k-th + ties) THEN deterministic
// compaction, one block per graph.
__global__ __launch_bounds__(1024) void k_topk(
    const unsigned* __restrict__ u, const float* __restrict__ score,
    int R, int Ksel, int* __restrict__ newid, int* __restrict__ oldid,
    float* __restrict__ scale){
  __shared__ int hist[2048];
  __shared__ int seg[32];
  __shared__ int sh_b, sh_k;
  __shared__ int wsA[16], wsB[16];
  __shared__ int carr0, carr1;
  int g = blockIdx.x, tid = threadIdx.x, lane = tid&63, w = tid>>6;
  const unsigned* ug = u + (size_t)g*R;
  // ---- phase 1: select
  unsigned prefix = 0;
  int K = Ksel;
  for(int lev=0; lev<3; lev++){
    int shf = (lev==0)?21:((lev==1)?10:0);
    int nb  = (lev==2)?1024:2048;
    for(int i=tid;i<2048;i+=1024) hist[i]=0;
    __syncthreads();
    for(int i=tid;i<R;i+=1024){
      unsigned v = ug[i];
      bool ok = (lev==0) || (lev==1 && (v>>21)==prefix) || (lev==2 && (v>>10)==prefix);
      if(ok) atomicAdd(&hist[(v>>shf)&(nb-1)], 1);
    }
    __syncthreads();
    int W = nb/32;
    if(tid<32){ int s=0; int lo=nb-W*(tid+1); for(int b=lo;b<lo+W;b++) s+=hist[b]; seg[tid]=s; }
    __syncthreads();
    if(tid==0){
      int kk=K, sgi=0;
      while(seg[sgi]<kk){ kk-=seg[sgi]; sgi++; }
      int b = nb-1-W*sgi;
      while(hist[b]<kk){ kk-=hist[b]; b--; }
      sh_b=b; sh_k=kk;
    }
    __syncthreads();
    int b = sh_b; K = sh_k;
    if(lev==0) prefix = (unsigned)b;
    else if(lev==1) prefix = (prefix<<11) | (unsigned)b;
    else prefix = (prefix<<10) | (unsigned)b;
    __syncthreads();
  }
  unsigned thr = prefix;
  int need = K;
  // ---- phase 2: compact (u>thr plus lowest-index u==thr; lax.top_k ties)
  if(tid==0){ carr0=0; carr1=0; }
  __syncthreads();
  for(int bb=0; bb<R; bb+=1024){
    int i = bb + tid; bool in = i < R;
    unsigned uv = in ? ug[i] : 0u;
    int eq = (in && uv==thr) ? 1:0;
    int gt = (in && uv>thr) ? 1:0;
    int inc = eq;
    for(int o=1;o<64;o<<=1){ int t=__shfl_up(inc,o,64); if(lane>=o) inc+=t; }
    if(lane==63) wsA[w]=inc;
    __syncthreads();
    int wb=0; for(int k=0;k<w;k++) wb+=wsA[k];
    int eq_excl = carr0 + wb + inc - eq;
    int take = (gt || (eq && eq_excl<need)) ? 1 : 0;
    int inc2 = take;
    for(int o=1;o<64;o<<=1){ int t=__shfl_up(inc2,o,64); if(lane>=o) inc2+=t; }
    if(lane==63) wsB[w]=inc2;
    __syncthreads();
    int wb2=0; for(int k=0;k<w;k++) wb2+=wsB[k];
    int pos = carr1 + wb2 + inc2 - take;
    if(take){
      int nr = g*Ksel + pos;
      newid[(size_t)g*R+i] = nr;
      oldid[nr] = g*R+i;
      scale[nr] = score[(size_t)g*R+i];
    }
    __syncthreads();
    if(tid==1023){ carr0 += wb + inc; carr1 += wb2 + inc2; }
    __syncthreads();
  }
}

// fused gate pipeline with stage-3 inorm on input:
// gatev = elu(norm(X)@gw1+gb1) . gw2 + gb2
__global__ __launch_bounds__(256) void k_gate_fused(
    const float* __restrict__ X, const float* __restrict__ accum,
    const float* __restrict__ gw1, const float* __restrict__ gb1,
    const float* __restrict__ gw2, const float* __restrict__ gb2,
    float* __restrict__ gatev, int n){
  __shared__ float xs[4][256];
  int tid = threadIdx.x;
  int n0 = blockIdx.x*4;
  for(int idx=tid; idx<1024; idx+=256){
    int r = idx >> 8, k = idx & 255;
    int row = n0 + r;
    float v = 0.f;
    if(row < n){
      int g = row / KP2;
      v = inorm_of(accum, g*256+k, (float)KP2, X[(size_t)row*256 + k]);
    }
    xs[r][k] = v;
  }
  __syncthreads();
  int sg = tid >> 6, c = tid & 63;
  float a = 0.f;
#pragma unroll 8
  for(int k=0;k<256;k++) a = fmaf(xs[sg][k], gw1[k*64+c], a);
  a = eluf(a + gb1[c]);
  float v = a * gw2[c];
#pragma unroll
  for(int o=32;o>0;o>>=1) v += __shfl_down(v, o, 64);
  if(c==0){
    int row = n0 + sg;
    if(row < n) gatev[row] = v + gb2[0];
  }
}

// MERGED h-GEMM + attention accumulate
__global__ __launch_bounds__(256) void k_attn_gemm(
    const float* __restrict__ X, const float* __restrict__ accum,
    const float* __restrict__ W, const float* __restrict__ bias,
    const float* __restrict__ gatev, float* __restrict__ gvec){
  __shared__ float xs[4][256];
  __shared__ float red[256];
  int tid = threadIdx.x;
  int t = blockIdx.x, g = blockIdx.y;
  int r0 = t*4;
  float mx = -1e30f;
  for(int r=tid;r<KP2;r+=256) mx = fmaxf(mx, gatev[g*KP2+r]);
  red[tid]=mx; __syncthreads();
  for(int s=128;s>0;s>>=1){ if(tid<s) red[tid]=fmaxf(red[tid],red[tid+s]); __syncthreads(); }
  mx = red[0]; __syncthreads();
  float sm=0.f;
  for(int r=tid;r<KP2;r+=256) sm += expf(gatev[g*KP2+r]-mx);
  red[tid]=sm; __syncthreads();
  for(int s=128;s>0;s>>=1){ if(tid<s) red[tid]+=red[tid+s]; __syncthreads(); }
  float inv = 1.f/red[0];
  __syncthreads();
  for(int idx=tid; idx<1024; idx+=256){
    int r = idx >> 8, k = idx & 255;
    int lr = r0 + r;
    float v = 0.f;
    if(lr < KP2){
      int row = g*KP2 + lr;
      v = inorm_of(accum, g*256+k, (float)KP2, X[(size_t)row*256 + k]);
    }
    xs[r][k] = v;
  }
  __syncthreads();
  int c = tid;
  float acc[4];
#pragma unroll
  for(int q=0;q<4;q++) acc[q]=0.f;
  for(int k=0;k<256;k++){
    float wv = W[(size_t)k*256 + c];
#pragma unroll
    for(int q=0;q<4;q++) acc[q] += xs[q][k]*wv;
  }
  float bv = bias[c];
  float tot = 0.f;
#pragma unroll
  for(int q=0;q<4;q++){
    int lr = r0 + q;
    if(lr < KP2){
      float h = eluf(acc[q] + bv);
      tot += expf(gatev[g*KP2+lr]-mx) * h;
    }
  }
  atomicAdd(&gvec[g*256+c], tot*inv);
}

// tiny-n tail MLP: compile-time K fully pipelined (R13: keep split — the
// 8-block merged tail regressed to latency-serialized weight streams)
template<int K,int CO,int ACT>
__global__ __launch_bounds__(256) void k_mlp_t(
    const float* __restrict__ X, const float* __restrict__ W,
    const float* __restrict__ b, float* __restrict__ Y, int n){
  int i = blockIdx.x*256+threadIdx.x;
  if(i>=n*CO) return;
  int r=i/CO, c=i%CO;
  const float* xr = X + (size_t)r*K;
  float a=0.f;
#pragma unroll 16
  for(int k=0;k<K;k++) a = fmaf(xr[k], W[(size_t)k*CO+c], a);
  a += b[c];
  if(ACT) a = eluf(a);
  Y[i]=a;
}

__global__ __launch_bounds__(64) void k_head(
    const float* __restrict__ z2, const float* __restrict__ w3,
    const float* __restrict__ b3, float* __restrict__ out){
  __shared__ float zc[10]; __shared__ float mred, sred;
  int g=blockIdx.x, tid=threadIdx.x;
  if(tid<10){
    float a=0.f;
#pragma unroll 16
    for(int k=0;k<128;k++) a += z2[g*128+k]*w3[k*10+tid];
    zc[tid]=a+b3[tid];
  }
  __syncthreads();
  if(tid==0){
    float m=zc[0];
    for(int k=1;k<10;k++) m=fmaxf(m,zc[k]);
    float s=0.f;
    for(int k=0;k<10;k++) s+=expf(zc[k]-m);
    mred=m; sred=logf(s);
  }
  __syncthreads();
  if(tid<10) out[g*10+tid]=zc[tid]-mred-sred;
}

} // namespace pk

extern "C" void kernel_launch(void* const* d_in, const int* in_sizes, int n_in,
                              void* d_out, int out_size, void* d_ws, size_t ws_size,
                              hipStream_t stream){
  using namespace pk;
  (void)in_sizes; (void)n_in; (void)out_size;
  const float* pos = (const float*)d_in[0];
  const int*   src = (const int*)d_in[1];
  const int*   dst = (const int*)d_in[2];
  const float* W1  = (const float*)d_in[3];
  const float* as1 = (const float*)d_in[4];
  const float* ad1 = (const float*)d_in[5];
  const float* b1  = (const float*)d_in[6];
  const float* p1  = (const float*)d_in[7];
  const float* W2  = (const float*)d_in[8];
  const float* as2 = (const float*)d_in[9];
  const float* ad2 = (const float*)d_in[10];
  const float* b2  = (const float*)d_in[11];
  const float* p2  = (const float*)d_in[12];
  const float* W3  = (const float*)d_in[13];
  const float* as3 = (const float*)d_in[14];
  const float* ad3 = (const float*)d_in[15];
  const float* b3  = (const float*)d_in[16];
  const float* gw1 = (const float*)d_in[17];
  const float* gb1 = (const float*)d_in[18];
  const float* gw2 = (const float*)d_in[19];
  const float* gb2 = (const float*)d_in[20];
  const float* aw  = (const float*)d_in[21];
  const float* ab  = (const float*)d_in[22];
  const float* w1  = (const float*)d_in[23];
  const float* bb1 = (const float*)d_in[24];
  const float* w2  = (const float*)d_in[25];
  const float* bb2 = (const float*)d_in[26];
  const float* w3  = (const float*)d_in[27];
  const float* bb3 = (const float*)d_in[28];
  float* out = (float*)d_out;

  char* base = (char*)d_ws; size_t off = 0;
  auto alloc = [&](size_t nbytes)->char*{
    char* p = base + off; off = (off + nbytes + 255) & ~(size_t)255; return p;
  };
  // --- zero-init region (one memset) ---
  int*   cnt2  = (int*)alloc((size_t)NN2*4);
  int*   cnt3  = (int*)alloc((size_t)NN3*4);
  int*   ecnt2 = (int*)alloc((size_t)BG*4);
  int*   ecnt3 = (int*)alloc((size_t)BG*4);
  float* acc1  = (float*)alloc((size_t)BG*32*2*4);
  float* acc2  = (float*)alloc((size_t)BG*128*2*4);
  float* acc3  = (float*)alloc((size_t)BG*256*2*4);
  float* gvec  = (float*)alloc((size_t)BG*256*4);
  size_t zend = off;
  // --- 0xFF-init region (newid = -1, one memset) ---
  int*   newid1 = (int*)alloc((size_t)NB1*4);
  int*   newid2 = (int*)alloc((size_t)NN2*4);
  size_t fstart = (size_t)((char*)newid1 - base);
  size_t fend = off;
  // --- plain scratch ---
  int*      cnt1   = (int*)alloc((size_t)NB1*4);   // dense-written
  float*    xp1    = (float*)alloc((size_t)NB1*32*4);
  float*    als1   = (float*)alloc((size_t)NB1*2*4);
  float*    ald1   = (float*)alloc((size_t)NB1*2*4);
  int*      rowptr1= (int*)alloc((size_t)NB1*4);
  int*      esrc1  = (int*)alloc((size_t)NE*4);
  float*    out1   = (float*)alloc((size_t)NB1*32*4);
  float*    score1 = (float*)alloc((size_t)NB1*4);
  unsigned* u1     = (unsigned*)alloc((size_t)NB1*4);
  int*      oldid1 = (int*)alloc((size_t)NN2*4);
  float*    scale1 = (float*)alloc((size_t)NN2*4);
  int*      ns2    = (int*)alloc((size_t)CAP2*4);
  int*      nd2    = (int*)alloc((size_t)CAP2*4);
  int*      rowptr2= (int*)alloc((size_t)NN2*4);
  int*      cursor2= (int*)alloc((size_t)NN2*4);
  int*      esrc2  = (int*)alloc((size_t)CAP2*4);
  float*    xp2    = (float*)alloc((size_t)NN2*128*4);
  float*    als2   = (float*)alloc((size_t)NN2*2*4);
  float*    ald2   = (float*)alloc((size_t)NN2*2*4);
  float*    out2   = (float*)alloc((size_t)NN2*128*4);
  float*    score2 = (float*)alloc((size_t)NN2*4);
  unsigned* u2     = (unsigned*)alloc((size_t)NN2*4);
  int*      oldid2 = (int*)alloc((size_t)NN3*4);
  float*    scale2 = (float*)alloc((size_t)NN3*4);
  int*      ns3    = (int*)alloc((size_t)CAP3*4);
  int*      nd3    = (int*)alloc((size_t)CAP3*4);
  int*      rowptr3= (int*)alloc((size_t)NN3*4);
  int*      cursor3= (int*)alloc((size_t)NN3*4);
  int*      esrc3  = (int*)alloc((size_t)CAP3*4);
  float*    xp3    = (float*)alloc((size_t)NN3*256*4);
  float*    als3   = (float*)alloc((size_t)NN3*4);
  float*    ald3   = (float*)alloc((size_t)NN3*4);
  float*    out3   = (float*)alloc((size_t)NN3*256*4);
  float*    gatev  = (float*)alloc((size_t)NN3*4);
  float*    z1     = (float*)alloc((size_t)BG*512*4);
  float*    z2     = (float*)alloc((size_t)BG*128*4);
  if(off > ws_size) return;  // workspace too small: fail visibly

  auto cdiv = [](int a, int b){ return (a+b-1)/b; };

  hipMemsetAsync(base, 0, zend, stream);
  hipMemsetAsync(base + fstart, 0xFF, fend - fstart, stream);

  // ---------------- stage 1: GAT(3->32, H=2,F=16) ----------------
  k_xp1<<<cdiv(NB1,256),256,0,stream>>>(pos,W1,as1,ad1,xp1,als1,ald1);
  k_tile_count<<<256,1024,0,stream>>>(dst,cnt1);
  k_scan_g<<<BG,1024,0,stream>>>(cnt1,NPG1,EPG1,rowptr1,nullptr);
  k_tile_scatter<<<256,1024,0,stream>>>(src,dst,rowptr1,esrc1);
  k_gat_fused<2,16,768><<<NB1/32,256,0,stream>>>(xp1,als1,ald1,rowptr1,cnt1,esrc1,b1,out1,acc1,NPG1,NB1);
  k_inorm_score<32><<<cdiv(NB1*32,256),256,0,stream>>>(out1,acc1,p1,8192,NB1*32,score1,u1);
  // ---------------- pool 1 (k=2458) ----------------
  k_topk<<<BG,1024,0,stream>>>(u1,score1,8192,KP1,newid1,oldid1,scale1);
  k_edge_compact<<<BG*32,256,0,stream>>>(src,dst,nullptr,EPG1,32,EPG1,newid1,ecnt2,ns2,nd2,REG2,cnt2);
  // ---------------- stage 2: GAT(32->128, H=2,F=64) ----------------
  k_scan_g<<<BG,1024,0,stream>>>(cnt2,KP1,REG2,rowptr2,cursor2);
  k_scatter_r<<<CAP2/256,256,0,stream>>>(ns2,nd2,ecnt2,REG2,cursor2,esrc2);
  k_gemm_al<32,128,4,2><<<cdiv(NN2,8),256,0,stream>>>(out1,oldid1,scale1,W2,xp2,as2,ad2,als2,ald2,NN2);
  k_gat_fused<2,64,256><<<NN2/8,256,0,stream>>>(xp2,als2,ald2,rowptr2,cnt2,esrc2,b2,out2,acc2,KP1,NN2);
  k_inorm_score<128><<<cdiv(NN2*128,256),256,0,stream>>>(out2,acc2,p2,KP1,NN2*128,score2,u2);
  // ---------------- pool 2 (k=738) ----------------
  k_topk<<<BG,1024,0,stream>>>(u2,score2,KP1,KP2,newid2,oldid2,scale2);
  k_edge_compact<<<BG*4,256,0,stream>>>(ns2,nd2,ecnt2,0,4,REG2,newid2,ecnt3,ns3,nd3,REG3,cnt3);
  // ---------------- stage 3: GAT(128->256, H=1,F=256) ----------------
  k_scan_g<<<BG,1024,0,stream>>>(cnt3,KP2,REG3,rowptr3,cursor3);
  k_scatter_r<<<CAP3/256,256,0,stream>>>(ns3,nd3,ecnt3,REG3,cursor3,esrc3);
  k_gemm_al<128,256,4,1><<<cdiv(NN3,4),256,0,stream>>>(out2,oldid2,scale2,W3,xp3,as3,ad3,als3,ald3,NN3);
  k_gat_fused<1,256,128><<<NN3/4,256,0,stream>>>(xp3,als3,ald3,rowptr3,cnt3,esrc3,b3,out3,acc3,KP2,NN3);
  // ---------------- global attention + MLP head (stage-3 norm fused in) ----
  k_gate_fused<<<cdiv(NN3,4),256,0,stream>>>(out3,acc3,gw1,gb1,gw2,gb2,gatev,NN3);
  k_attn_gemm<<<dim3(cdiv(KP2,4),BG),256,0,stream>>>(out3,acc3,aw,ab,gatev,gvec);
  k_mlp_t<256,512,1><<<cdiv(BG*512,256),256,0,stream>>>(gvec,w1,bb1,z1,BG);
  k_mlp_t<512,128,1><<<cdiv(BG*128,256),256,0,stream>>>(z1,w2,bb2,z2,BG);
  k_head<<<BG,64,0,stream>>>(z2,w3,bb3,out);
}

// Round 18
// 459.525 us; speedup vs baseline: 1.0817x; 1.0817x over previous
//
#include <hip/hip_runtime.h>
#include <cstdint>
#include <cstddef>

#define DI __device__ __forceinline__

namespace pk {

constexpr int NB1 = 65536;      // stage-1 nodes (B*N)
constexpr int NE  = 1048576;    // edges (B*N*DEG)
constexpr int BG  = 8;          // graphs
constexpr int NPG1 = 8192;      // nodes per graph, stage 1
constexpr int EPG1 = NE/BG;     // edges per graph, stage 1 (131072)
constexpr int KP1 = 2458;       // top-k 1
constexpr int KP2 = 738;        // top-k 2
constexpr int NN2 = BG*KP1;     // 19664
constexpr int NN3 = BG*KP2;     // 5904
constexpr int REG2 = 16384;     // per-graph edge region after pool1 (exp 11.8K±0.1K)
constexpr int REG3 = 4096;      // per-graph edge region after pool2 (exp ~1.1K)
constexpr int CAP2 = BG*REG2;
constexpr int CAP3 = BG*REG3;

DI float lrelu(float x){ return x > 0.f ? x : 0.2f*x; }
DI float eluf(float x){ return x > 0.f ? x : expf(x) - 1.f; }

// XCD-affinity swizzle (heuristic only).
DI int swz_block(){
  int nb = gridDim.x, b = blockIdx.x;
  if((nb & 7) == 0) return (b & 7)*(nb >> 3) + (b >> 3);
  return b;
}

// ---- stage-1 projection: xp = pos @ W1 (K=3), plus attention logits per head
__global__ __launch_bounds__(256) void k_xp1(
    const float* __restrict__ pos, const float* __restrict__ W,
    const float* __restrict__ as_, const float* __restrict__ ad_,
    float* __restrict__ xp, float* __restrict__ als, float* __restrict__ ald){
  int i = blockIdx.x*256 + threadIdx.x;
  if(i >= NB1) return;
  float p0=pos[3*i], p1=pos[3*i+1], p2=pos[3*i+2];
  float row[32];
#pragma unroll
  for(int c=0;c<32;c++) row[c] = p0*W[c] + p1*W[32+c] + p2*W[64+c];
  float s0=0.f,d0=0.f,s1=0.f,d1=0.f;
#pragma unroll
  for(int f=0;f<16;f++){
    s0 += row[f]*as_[f];        d0 += row[f]*ad_[f];
    s1 += row[16+f]*as_[16+f];  d1 += row[16+f]*ad_[16+f];
  }
  float4* o = reinterpret_cast<float4*>(xp + (size_t)i*32);
#pragma unroll
  for(int q=0;q<8;q++) o[q] = make_float4(row[4*q],row[4*q+1],row[4*q+2],row[4*q+3]);
  als[2*i]=s0; als[2*i+1]=s1; ald[2*i]=d0; ald[2*i+1]=d1;
}

// ---- stage-1 dst-tiled CSR build
__global__ __launch_bounds__(1024) void k_tile_count(
    const int* __restrict__ de, int* __restrict__ cnt){
  __shared__ int h[256];
  int tid = threadIdx.x;
  int g = blockIdx.x & 7, t = blockIdx.x >> 3;
  int lo = g*NPG1 + t*256;
  if(tid < 256) h[tid] = 0;
  __syncthreads();
  const int4* de4 = (const int4*)(de + g*EPG1);   // 32768 int4s per graph
  for(int it=0; it<4; it++){
    int4 buf[8];
#pragma unroll
    for(int j=0;j<8;j++) buf[j] = de4[(it*8+j)*1024 + tid];
#pragma unroll
    for(int j=0;j<8;j++){
      int4 b = buf[j];
      int d0=b.x-lo, d1=b.y-lo, d2=b.z-lo, d3=b.w-lo;
      if((unsigned)d0<256u) atomicAdd(&h[d0],1);
      if((unsigned)d1<256u) atomicAdd(&h[d1],1);
      if((unsigned)d2<256u) atomicAdd(&h[d2],1);
      if((unsigned)d3<256u) atomicAdd(&h[d3],1);
    }
  }
  __syncthreads();
  if(tid < 256) cnt[lo + tid] = h[tid];
}

__global__ __launch_bounds__(1024) void k_tile_scatter(
    const int* __restrict__ se, const int* __restrict__ de,
    const int* __restrict__ rowptr, int* __restrict__ eo){
  __shared__ int cur[256];
  int tid = threadIdx.x;
  int g = blockIdx.x & 7, t = blockIdx.x >> 3;
  int lo = g*NPG1 + t*256;
  if(tid < 256) cur[tid] = rowptr[lo + tid];
  __syncthreads();
  const int4* de4 = (const int4*)(de + g*EPG1);
  const int4* se4 = (const int4*)(se + g*EPG1);
  for(int it=0; it<4; it++){
    int4 bd[8], bs[8];
#pragma unroll
    for(int j=0;j<8;j++){
      int idx = (it*8+j)*1024 + tid;
      bd[j] = de4[idx]; bs[j] = se4[idx];
    }
#pragma unroll
    for(int j=0;j<8;j++){
      int4 d = bd[j], s = bs[j];
      int d0=d.x-lo; if((unsigned)d0<256u){ int p=atomicAdd(&cur[d0],1); eo[p]=s.x; }
      int d1=d.y-lo; if((unsigned)d1<256u){ int p=atomicAdd(&cur[d1],1); eo[p]=s.y; }
      int d2=d.z-lo; if((unsigned)d2<256u){ int p=atomicAdd(&cur[d2],1); eo[p]=s.z; }
      int d3=d.w-lo; if((unsigned)d3<256u){ int p=atomicAdd(&cur[d3],1); eo[p]=s.w; }
    }
  }
}

// per-graph-region atomic scatter (stages 2/3)
__global__ __launch_bounds__(256) void k_scatter_r(
    const int* __restrict__ se, const int* __restrict__ de,
    const int* __restrict__ gcnt, int reg,
    int* __restrict__ cursor, int* __restrict__ eo){
  int i = swz_block()*256 + threadIdx.x;
  int g = i / reg, loc = i % reg;
  if(loc < gcnt[g]){
    int p = atomicAdd(&cursor[de[i]], 1);
    eo[p] = se[i];
  }
}

// stream compaction into PER-GRAPH regions, fused degree count.
__global__ __launch_bounds__(256) void k_edge_compact(
    const int* __restrict__ se, const int* __restrict__ de,
    const int* __restrict__ gcnt_in, int fixed_in, int bpg, int reg_in,
    const int* __restrict__ newid, int* __restrict__ gcnt_out,
    int* __restrict__ ons, int* __restrict__ ond, int reg_out,
    int* __restrict__ cnt){
  __shared__ int s_a[4096];
  __shared__ int s_b[4096];
  __shared__ int run, tbase;
  int tid = threadIdx.x;
  if(tid == 0) run = 0;
  __syncthreads();
  int blk = swz_block();
  int g = blk / bpg, t = blk % bpg;
  int mg = gcnt_in ? gcnt_in[g] : fixed_in;
  if(mg > reg_in) mg = reg_in;
  int base_l = t*4096;
  if(base_l < mg){
    const int* deb = de + (size_t)g*reg_in + base_l;
    const int* seb = se + (size_t)g*reg_in + base_l;
    const int4* de4 = (const int4*)deb;
    const int4* se4 = (const int4*)seb;
    int4 BD[4], BS[4];
#pragma unroll
    for(int j=0;j<4;j++){ BD[j]=de4[j*256+tid]; BS[j]=se4[j*256+tid]; }
#pragma unroll
    for(int j=0;j<4;j++){
      int eb = base_l + (j*256+tid)*4;
      int dd[4]={BD[j].x,BD[j].y,BD[j].z,BD[j].w};
      int ss[4]={BS[j].x,BS[j].y,BS[j].z,BS[j].w};
#pragma unroll
      for(int q=0;q<4;q++){
        if(eb+q < mg){
          int a = newid[ss[q]], b = newid[dd[q]];
          if(a>=0 && b>=0){
            int p = atomicAdd(&run, 1);
            s_a[p]=a; s_b[p]=b;
            atomicAdd(&cnt[b], 1);
          }
        }
      }
    }
  }
  __syncthreads();
  int ns = run;
  if(tid==0) tbase = ns ? atomicAdd(&gcnt_out[g], ns) : 0;
  __syncthreads();
  int tb = tbase;
  for(int j=tid; j<ns; j+=256){
    int s2 = tb + j;
    if(s2 < reg_out){ ons[(size_t)g*reg_out+s2]=s_a[j]; ond[(size_t)g*reg_out+s2]=s_b[j]; }
  }
}

// per-graph single-block exclusive scan (one dispatch; graphs independent)
__global__ __launch_bounds__(1024) void k_scan_g(
    const int* __restrict__ cnt, int R, int estride,
    int* __restrict__ rowptr, int* __restrict__ cursor){
  __shared__ int wsum[16];
  int g = blockIdx.x;
  int tid = threadIdx.x, lane = tid & 63, w = tid >> 6;
  int PER = (R + 1023) >> 10;
  int base = g*R;
  int i0 = tid*PER;
  int v[8]; int s = 0;
  for(int j=0;j<PER;j++){ int i=i0+j; int x=(i<R)?cnt[base+i]:0; v[j]=s; s+=x; }
  int inc = s;
  for(int o=1;o<64;o<<=1){ int t=__shfl_up(inc,o,64); if(lane>=o) inc+=t; }
  if(lane==63) wsum[w]=inc;
  __syncthreads();
  int wb=0;
  for(int k=0;k<w;k++) wb+=wsum[k];
  int tb = g*estride + wb + inc - s;
  for(int j=0;j<PER;j++){
    int i=i0+j;
    if(i<R){
      int e=tb+v[j];
      rowptr[base+i]=e;
      if(cursor) cursor[base+i]=e;
    }
  }
}

// FUSED GAT: weights (lane-parallel into LDS) + softmax-normalized aggregate
// + fused inorm stats v2: WAVE SHUFFLE reduce (R17's LDS atomics had 32-way
// same-address contention -> stage-1 regressed to 62us; shuffles are free).
// Same-channel lanes sit at stride C4 in a wave; fold to lane<C4, per-wave
// LDS slot (plain store), tid<C sums 4 partials -> 1 global atomic pair.
template<int H,int F,int ECAP>
__global__ __launch_bounds__(256) void k_gat_fused(
    const float* __restrict__ xp, const float* __restrict__ als,
    const float* __restrict__ ald, const int* __restrict__ rowptr,
    const int* __restrict__ cnt, const int* __restrict__ esrc,
    const float* __restrict__ bias, float* __restrict__ out,
    float* __restrict__ accum, int RPG, int n){
  constexpr int C = H*F, C4 = C/4, NPB = 256/C4;
  __shared__ int rst[NPB];
  __shared__ int ecum[NPB+1];
  __shared__ float aldv[NPB*H];
  __shared__ float wselfs[NPB*H];
  __shared__ float dens[NPB*H];
  __shared__ float wexps[ECAP*H];
  __shared__ float psum[4][C], psq[4][C];
  int tid = threadIdx.x;
  int node0 = swz_block()*NPB;
  if(tid < NPB){
    int node = node0 + tid;
    rst[tid] = (node < n) ? rowptr[node] : 0;
  }
  if(tid < 64){
    int d = (tid < NPB && node0+tid < n) ? cnt[node0+tid] : 0;
    int inc = d;
    for(int o=1;o<64;o<<=1){ int t2=__shfl_up(inc,o,64); if(tid>=o) inc+=t2; }
    if(tid < NPB) ecum[tid] = inc - d;
    if(tid == NPB-1) ecum[NPB] = inc;
  }
  if(tid < NPB*H){
    int node = node0 + tid/H, h = tid%H;
    float dv = 0.f, sw = 0.f;
    if(node < n){ dv = ald[node*H+h]; sw = expf(lrelu(als[node*H+h] + dv)); }
    aldv[tid]=dv; wselfs[tid]=sw; dens[tid]=sw;
  }
  __syncthreads();
  int totE = ecum[NPB];
  for(int s=tid; s<totE; s+=256){
    int lo=0, hi=NPB;
    while(hi-lo > 1){ int mid=(lo+hi)>>1; if(ecum[mid] <= s) lo=mid; else hi=mid; }
    int k = rst[lo] + (s - ecum[lo]);
    int srcn = esrc[k];
    if(H == 2){
      float2 a = ((const float2*)als)[srcn];
      float e0 = expf(lrelu(a.x + aldv[lo*2]));
      float e1 = expf(lrelu(a.y + aldv[lo*2+1]));
      if(s < ECAP){ wexps[s*2]=e0; wexps[s*2+1]=e1; }
      atomicAdd(&dens[lo*2], e0);
      atomicAdd(&dens[lo*2+1], e1);
    } else {
      float e0 = expf(lrelu(als[srcn] + aldv[lo]));
      if(s < ECAP) wexps[s]=e0;
      atomicAdd(&dens[lo], e0);
    }
  }
  __syncthreads();
  int nl = tid / C4, p = tid % C4;
  int node = node0 + nl;
  int hh = (4*p)/F;
  const float4* xp4 = (const float4*)xp;
  float4 r = make_float4(0.f,0.f,0.f,0.f);
  bool valid = node < n;
  if(valid){
    float4 xs = xp4[(size_t)node*C4 + p];
    float sw = wselfs[nl*H+hh];
    float ax=sw*xs.x, ay=sw*xs.y, az=sw*xs.z, aw_=sw*xs.w;
    int r0 = rst[nl], e0o = ecum[nl], deg = ecum[nl+1]-e0o;
    float dvh = aldv[nl*H+hh];
#pragma unroll 4
    for(int j=0;j<deg;j++){
      int s = e0o + j;
      int srcn = esrc[r0+j];
      float w = (s < ECAP) ? wexps[s*H+hh]
                           : expf(lrelu(als[srcn*H+hh] + dvh));
      float4 v = xp4[(size_t)srcn*C4 + p];
      ax+=w*v.x; ay+=w*v.y; az+=w*v.z; aw_+=w*v.w;
    }
    float inv = 1.f / dens[nl*H+hh];
    float4 bv = ((const float4*)bias)[p];
    r.x=ax*inv+bv.x; r.y=ay*inv+bv.y; r.z=az*inv+bv.z; r.w=aw_*inv+bv.w;
    ((float4*)out)[(size_t)node*C4 + p] = r;
  }
  // ---- fused inorm stats v2 (block-uniform branch; invalid lanes hold r=0)
  int g0 = node0 / RPG;
  bool straddle = ((node0 + NPB - 1) / RPG) != g0;
  if(straddle){
    if(valid){
      int g = node / RPG;
      atomicAdd(&accum[(g*C+4*p+0)*2], r.x); atomicAdd(&accum[(g*C+4*p+0)*2+1], r.x*r.x);
      atomicAdd(&accum[(g*C+4*p+1)*2], r.y); atomicAdd(&accum[(g*C+4*p+1)*2+1], r.y*r.y);
      atomicAdd(&accum[(g*C+4*p+2)*2], r.z); atomicAdd(&accum[(g*C+4*p+2)*2+1], r.z*r.z);
      atomicAdd(&accum[(g*C+4*p+3)*2], r.w); atomicAdd(&accum[(g*C+4*p+3)*2+1], r.w*r.w);
    }
  } else {
    float sx=r.x, sy=r.y, sz=r.z, sw2=r.w;
    float qx=r.x*r.x, qy=r.y*r.y, qz=r.z*r.z, qw=r.w*r.w;
#pragma unroll
    for(int off=C4; off<64; off<<=1){
      sx += __shfl_down(sx, off, 64); sy += __shfl_down(sy, off, 64);
      sz += __shfl_down(sz, off, 64); sw2 += __shfl_down(sw2, off, 64);
      qx += __shfl_down(qx, off, 64); qy += __shfl_down(qy, off, 64);
      qz += __shfl_down(qz, off, 64); qw += __shfl_down(qw, off, 64);
    }
    int lane = tid & 63, w = tid >> 6;
    if(lane < C4){
      psum[w][4*lane+0]=sx; psum[w][4*lane+1]=sy;
      psum[w][4*lane+2]=sz; psum[w][4*lane+3]=sw2;
      psq[w][4*lane+0]=qx;  psq[w][4*lane+1]=qy;
      psq[w][4*lane+2]=qz;  psq[w][4*lane+3]=qw;
    }
    __syncthreads();
    if(tid < C){
      float ts = psum[0][tid]+psum[1][tid]+psum[2][tid]+psum[3][tid];
      float tq = psq[0][tid]+psq[1][tid]+psq[2][tid]+psq[3][tid];
      atomicAdd(&accum[(g0*C+tid)*2],   ts);
      atomicAdd(&accum[(g0*C+tid)*2+1], tq);
    }
  }
}

// dense row-GEMM with fused POOL-GATHER input (X[oldid[row]]*scale[row]) and
// fused attention-logit epilogue.
template<int K,int CO,int NPG,int H>
__global__ __launch_bounds__(256) void k_gemm_al(
    const float* __restrict__ X, const int* __restrict__ oldid,
    const float* __restrict__ scale, const float* __restrict__ W,
    float* __restrict__ Y, const float* __restrict__ a_s,
    const float* __restrict__ a_d, float* __restrict__ als,
    float* __restrict__ ald, int n){
  constexpr int SUB = 256/CO;
  constexpr int NB = SUB*NPG;
  __shared__ float xs[NB][K];
  __shared__ float ps[4][NPG], pd[4][NPG];
  int tid = threadIdx.x;
  int c = tid % CO, sg = tid / CO;
  int n0 = blockIdx.x * NB;
  for(int idx=tid; idx<NB*K; idx+=256){
    int r = idx / K, k = idx % K;
    int row = n0 + r;
    float v = 0.f;
    if(row < n){
      int orow = oldid[row];
      v = X[(size_t)orow*K + k] * scale[row];
    }
    xs[r][k] = v;
  }
  __syncthreads();
  float acc[NPG];
#pragma unroll
  for(int q=0;q<NPG;q++) acc[q]=0.f;
  for(int k=0;k<K;k++){
    float wv = W[(size_t)k*CO + c];
#pragma unroll
    for(int q=0;q<NPG;q++) acc[q] += xs[sg*NPG+q][k]*wv;
  }
  float asc = a_s[c], adc = a_d[c];
  float vs[NPG], vd[NPG];
#pragma unroll
  for(int q=0;q<NPG;q++){
    int row = n0 + sg*NPG + q;
    if(row < n) Y[(size_t)row*CO + c] = acc[q];
    vs[q] = acc[q]*asc; vd[q] = acc[q]*adc;
  }
#pragma unroll
  for(int o=32;o>0;o>>=1){
#pragma unroll
    for(int q=0;q<NPG;q++){
      vs[q] += __shfl_down(vs[q], o, 64);
      vd[q] += __shfl_down(vd[q], o, 64);
    }
  }
  int lane = tid & 63, w = tid >> 6;
  if(H == 2){
    if(lane == 0){
      int sg_ = w >> 1, h = w & 1;
#pragma unroll
      for(int q=0;q<NPG;q++){
        int row = n0 + sg_*NPG + q;
        if(row < n){ als[row*2+h] = vs[q]; ald[row*2+h] = vd[q]; }
      }
    }
  } else {
    if(lane == 0){
#pragma unroll
      for(int q=0;q<NPG;q++){ ps[w][q]=vs[q]; pd[w][q]=vd[q]; }
    }
    __syncthreads();
    if(tid < NPG){
      float s=0.f, d=0.f;
      for(int ww=0;ww<4;ww++){ s+=ps[ww][tid]; d+=pd[ww][tid]; }
      int row = n0 + tid;
      if(row < n){ als[row]=s; ald[row]=d; }
    }
  }
}

// inorm normalize helper from accum stats
DI float inorm_of(const float* accum, int gc, float R, float x){
  float s = accum[gc*2], sq = accum[gc*2+1];
  float mu = s / R;
  float var = fmaxf(sq/R - mu*mu, 0.f);
  return eluf((x-mu)*rsqrtf(var+1e-5f));
}

// fused inorm-apply + ELU + pool score + orderable key (stages 1/2).
template<int C>
__global__ __launch_bounds__(256) void k_inorm_score(
    float* __restrict__ x, const float* __restrict__ accum,
    const float* __restrict__ p, int R, int total,
    float* __restrict__ score, unsigned* __restrict__ u){
  __shared__ float rvp[256], rpp[256];
  int tid = threadIdx.x;
  int i = blockIdx.x*256 + tid;
  int c = tid & (C-1);
  bool act = i < total;
  float v = 0.f, pv = 0.f;
  if(act){
    int g = i / (R*C);
    v = inorm_of(accum, g*C+c, (float)R, x[i]);
    x[i] = v;
    pv = p[c];
  }
  rvp[tid] = v*pv; rpp[tid] = pv*pv;
  __syncthreads();
#pragma unroll
  for(int s2=C/2; s2>0; s2>>=1){
    if(c < s2){ rvp[tid]+=rvp[tid+s2]; rpp[tid]+=rpp[tid+s2]; }
    __syncthreads();
  }
  if(act && c==0){
    float sv = tanhf(rvp[tid]*rsqrtf(rpp[tid]));
    int row = i / C;
    score[row] = sv;
    unsigned bts = __float_as_uint(sv);
    u[row] = (bts & 0x80000000u) ? ~bts : (bts | 0x80000000u);
  }
}

// MERGED top-k: radix select (exact k-th + ties) THEN deterministic
// compaction, one block per graph.
__global__ __launch_bounds__(1024) void k_topk(
    const unsigned* __restrict__ u, const float* __restrict__ score,
    int R, int Ksel, int* __restrict__ newid, int* __restrict__ oldid,
    float* __restrict__ scale){
  __shared__ int hist[2048];
  __shared__ int seg[32];
  __shared__ int sh_b, sh_k;
  __shared__ int wsA[16], wsB[16];
  __shared__ int carr0, carr1;
  int g = blockIdx.x, tid = threadIdx.x, lane = tid&63, w = tid>>6;
  const unsigned* ug = u + (size_t)g*R;
  // ---- phase 1: select
  unsigned prefix = 0;
  int K = Ksel;
  for(int lev=0; lev<3; lev++){
    int shf = (lev==0)?21:((lev==1)?10:0);
    int nb  = (lev==2)?1024:2048;
    for(int i=tid;i<2048;i+=1024) hist[i]=0;
    __syncthreads();
    for(int i=tid;i<R;i+=1024){
      unsigned v = ug[i];
      bool ok = (lev==0) || (lev==1 && (v>>21)==prefix) || (lev==2 && (v>>10)==prefix);
      if(ok) atomicAdd(&hist[(v>>shf)&(nb-1)], 1);
    }
    __syncthreads();
    int W = nb/32;
    if(tid<32){ int s=0; int lo=nb-W*(tid+1); for(int b=lo;b<lo+W;b++) s+=hist[b]; seg[tid]=s; }
    __syncthreads();
    if(tid==0){
      int kk=K, sgi=0;
      while(seg[sgi]<kk){ kk-=seg[sgi]; sgi++; }
      int b = nb-1-W*sgi;
      while(hist[b]<kk){ kk-=hist[b]; b--; }
      sh_b=b; sh_k=kk;
    }
    __syncthreads();
    int b = sh_b; K = sh_k;
    if(lev==0) prefix = (unsigned)b;
    else if(lev==1) prefix = (prefix<<11) | (unsigned)b;
    else prefix = (prefix<<10) | (unsigned)b;
    __syncthreads();
  }
  unsigned thr = prefix;
  int need = K;
  // ---- phase 2: compact (u>thr plus lowest-index u==thr; lax.top_k ties)
  if(tid==0){ carr0=0; carr1=0; }
  __syncthreads();
  for(int bb=0; bb<R; bb+=1024){
    int i = bb + tid; bool in = i < R;
    unsigned uv = in ? ug[i] : 0u;
    int eq = (in && uv==thr) ? 1:0;
    int gt = (in && uv>thr) ? 1:0;
    int inc = eq;
    for(int o=1;o<64;o<<=1){ int t=__shfl_up(inc,o,64); if(lane>=o) inc+=t; }
    if(lane==63) wsA[w]=inc;
    __syncthreads();
    int wb=0; for(int k=0;k<w;k++) wb+=wsA[k];
    int eq_excl = carr0 + wb + inc - eq;
    int take = (gt || (eq && eq_excl<need)) ? 1 : 0;
    int inc2 = take;
    for(int o=1;o<64;o<<=1){ int t=__shfl_up(inc2,o,64); if(lane>=o) inc2+=t; }
    if(lane==63) wsB[w]=inc2;
    __syncthreads();
    int wb2=0; for(int k=0;k<w;k++) wb2+=wsB[k];
    int pos = carr1 + wb2 + inc2 - take;
    if(take){
      int nr = g*Ksel + pos;
      newid[(size_t)g*R+i] = nr;
      oldid[nr] = g*R+i;
      scale[nr] = score[(size_t)g*R+i];
    }
    __syncthreads();
    if(tid==1023){ carr0 += wb + inc; carr1 += wb2 + inc2; }
    __syncthreads();
  }
}

// fused gate pipeline with stage-3 inorm on input:
// gatev = elu(norm(X)@gw1+gb1) . gw2 + gb2
__global__ __launch_bounds__(256) void k_gate_fused(
    const float* __restrict__ X, const float* __restrict__ accum,
    const float* __restrict__ gw1, const float* __restrict__ gb1,
    const float* __restrict__ gw2, const float* __restrict__ gb2,
    float* __restrict__ gatev, int n){
  __shared__ float xs[4][256];
  int tid = threadIdx.x;
  int n0 = blockIdx.x*4;
  for(int idx=tid; idx<1024; idx+=256){
    int r = idx >> 8, k = idx & 255;
    int row = n0 + r;
    float v = 0.f;
    if(row < n){
      int g = row / KP2;
      v = inorm_of(accum, g*256+k, (float)KP2, X[(size_t)row*256 + k]);
    }
    xs[r][k] = v;
  }
  __syncthreads();
  int sg = tid >> 6, c = tid & 63;
  float a = 0.f;
#pragma unroll 8
  for(int k=0;k<256;k++) a = fmaf(xs[sg][k], gw1[k*64+c], a);
  a = eluf(a + gb1[c]);
  float v = a * gw2[c];
#pragma unroll
  for(int o=32;o>0;o>>=1) v += __shfl_down(v, o, 64);
  if(c==0){
    int row = n0 + sg;
    if(row < n) gatev[row] = v + gb2[0];
  }
}

// MERGED h-GEMM + attention accumulate
__global__ __launch_bounds__(256) void k_attn_gemm(
    const float* __restrict__ X, const float* __restrict__ accum,
    const float* __restrict__ W, const float* __restrict__ bias,
    const float* __restrict__ gatev, float* __restrict__ gvec){
  __shared__ float xs[4][256];
  __shared__ float red[256];
  int tid = threadIdx.x;
  int t = blockIdx.x, g = blockIdx.y;
  int r0 = t*4;
  float mx = -1e30f;
  for(int r=tid;r<KP2;r+=256) mx = fmaxf(mx, gatev[g*KP2+r]);
  red[tid]=mx; __syncthreads();
  for(int s=128;s>0;s>>=1){ if(tid<s) red[tid]=fmaxf(red[tid],red[tid+s]); __syncthreads(); }
  mx = red[0]; __syncthreads();
  float sm=0.f;
  for(int r=tid;r<KP2;r+=256) sm += expf(gatev[g*KP2+r]-mx);
  red[tid]=sm; __syncthreads();
  for(int s=128;s>0;s>>=1){ if(tid<s) red[tid]+=red[tid+s]; __syncthreads(); }
  float inv = 1.f/red[0];
  __syncthreads();
  for(int idx=tid; idx<1024; idx+=256){
    int r = idx >> 8, k = idx & 255;
    int lr = r0 + r;
    float v = 0.f;
    if(lr < KP2){
      int row = g*KP2 + lr;
      v = inorm_of(accum, g*256+k, (float)KP2, X[(size_t)row*256 + k]);
    }
    xs[r][k] = v;
  }
  __syncthreads();
  int c = tid;
  float acc[4];
#pragma unroll
  for(int q=0;q<4;q++) acc[q]=0.f;
  for(int k=0;k<256;k++){
    float wv = W[(size_t)k*256 + c];
#pragma unroll
    for(int q=0;q<4;q++) acc[q] += xs[q][k]*wv;
  }
  float bv = bias[c];
  float tot = 0.f;
#pragma unroll
  for(int q=0;q<4;q++){
    int lr = r0 + q;
    if(lr < KP2){
      float h = eluf(acc[q] + bv);
      tot += expf(gatev[g*KP2+lr]-mx) * h;
    }
  }
  atomicAdd(&gvec[g*256+c], tot*inv);
}

// tiny-n tail MLP: compile-time K fully pipelined (R13: keep split — the
// 8-block merged tail regressed to latency-serialized weight streams)
template<int K,int CO,int ACT>
__global__ __launch_bounds__(256) void k_mlp_t(
    const float* __restrict__ X, const float* __restrict__ W,
    const float* __restrict__ b, float* __restrict__ Y, int n){
  int i = blockIdx.x*256+threadIdx.x;
  if(i>=n*CO) return;
  int r=i/CO, c=i%CO;
  const float* xr = X + (size_t)r*K;
  float a=0.f;
#pragma unroll 16
  for(int k=0;k<K;k++) a = fmaf(xr[k], W[(size_t)k*CO+c], a);
  a += b[c];
  if(ACT) a = eluf(a);
  Y[i]=a;
}

__global__ __launch_bounds__(64) void k_head(
    const float* __restrict__ z2, const float* __restrict__ w3,
    const float* __restrict__ b3, float* __restrict__ out){
  __shared__ float zc[10]; __shared__ float mred, sred;
  int g=blockIdx.x, tid=threadIdx.x;
  if(tid<10){
    float a=0.f;
#pragma unroll 16
    for(int k=0;k<128;k++) a += z2[g*128+k]*w3[k*10+tid];
    zc[tid]=a+b3[tid];
  }
  __syncthreads();
  if(tid==0){
    float m=zc[0];
    for(int k=1;k<10;k++) m=fmaxf(m,zc[k]);
    float s=0.f;
    for(int k=0;k<10;k++) s+=expf(zc[k]-m);
    mred=m; sred=logf(s);
  }
  __syncthreads();
  if(tid<10) out[g*10+tid]=zc[tid]-mred-sred;
}

} // namespace pk

extern "C" void kernel_launch(void* const* d_in, const int* in_sizes, int n_in,
                              void* d_out, int out_size, void* d_ws, size_t ws_size,
                              hipStream_t stream){
  using namespace pk;
  (void)in_sizes; (void)n_in; (void)out_size;
  const float* pos = (const float*)d_in[0];
  const int*   src = (const int*)d_in[1];
  const int*   dst = (const int*)d_in[2];
  const float* W1  = (const float*)d_in[3];
  const float* as1 = (const float*)d_in[4];
  const float* ad1 = (const float*)d_in[5];
  const float* b1  = (const float*)d_in[6];
  const float* p1  = (const float*)d_in[7];
  const float* W2  = (const float*)d_in[8];
  const float* as2 = (const float*)d_in[9];
  const float* ad2 = (const float*)d_in[10];
  const float* b2  = (const float*)d_in[11];
  const float* p2  = (const float*)d_in[12];
  const float* W3  = (const float*)d_in[13];
  const float* as3 = (const float*)d_in[14];
  const float* ad3 = (const float*)d_in[15];
  const float* b3  = (const float*)d_in[16];
  const float* gw1 = (const float*)d_in[17];
  const float* gb1 = (const float*)d_in[18];
  const float* gw2 = (const float*)d_in[19];
  const float* gb2 = (const float*)d_in[20];
  const float* aw  = (const float*)d_in[21];
  const float* ab  = (const float*)d_in[22];
  const float* w1  = (const float*)d_in[23];
  const float* bb1 = (const float*)d_in[24];
  const float* w2  = (const float*)d_in[25];
  const float* bb2 = (const float*)d_in[26];
  const float* w3  = (const float*)d_in[27];
  const float* bb3 = (const float*)d_in[28];
  float* out = (float*)d_out;

  char* base = (char*)d_ws; size_t off = 0;
  auto alloc = [&](size_t nbytes)->char*{
    char* p = base + off; off = (off + nbytes + 255) & ~(size_t)255; return p;
  };
  // --- zero-init region (one memset) ---
  int*   cnt2  = (int*)alloc((size_t)NN2*4);
  int*   cnt3  = (int*)alloc((size_t)NN3*4);
  int*   ecnt2 = (int*)alloc((size_t)BG*4);
  int*   ecnt3 = (int*)alloc((size_t)BG*4);
  float* acc1  = (float*)alloc((size_t)BG*32*2*4);
  float* acc2  = (float*)alloc((size_t)BG*128*2*4);
  float* acc3  = (float*)alloc((size_t)BG*256*2*4);
  float* gvec  = (float*)alloc((size_t)BG*256*4);
  size_t zend = off;
  // --- 0xFF-init region (newid = -1, one memset) ---
  int*   newid1 = (int*)alloc((size_t)NB1*4);
  int*   newid2 = (int*)alloc((size_t)NN2*4);
  size_t fstart = (size_t)((char*)newid1 - base);
  size_t fend = off;
  // --- plain scratch ---
  int*      cnt1   = (int*)alloc((size_t)NB1*4);   // dense-written
  float*    xp1    = (float*)alloc((size_t)NB1*32*4);
  float*    als1   = (float*)alloc((size_t)NB1*2*4);
  float*    ald1   = (float*)alloc((size_t)NB1*2*4);
  int*      rowptr1= (int*)alloc((size_t)NB1*4);
  int*      esrc1  = (int*)alloc((size_t)NE*4);
  float*    out1   = (float*)alloc((size_t)NB1*32*4);
  float*    score1 = (float*)alloc((size_t)NB1*4);
  unsigned* u1     = (unsigned*)alloc((size_t)NB1*4);
  int*      oldid1 = (int*)alloc((size_t)NN2*4);
  float*    scale1 = (float*)alloc((size_t)NN2*4);
  int*      ns2    = (int*)alloc((size_t)CAP2*4);
  int*      nd2    = (int*)alloc((size_t)CAP2*4);
  int*      rowptr2= (int*)alloc((size_t)NN2*4);
  int*      cursor2= (int*)alloc((size_t)NN2*4);
  int*      esrc2  = (int*)alloc((size_t)CAP2*4);
  float*    xp2    = (float*)alloc((size_t)NN2*128*4);
  float*    als2   = (float*)alloc((size_t)NN2*2*4);
  float*    ald2   = (float*)alloc((size_t)NN2*2*4);
  float*    out2   = (float*)alloc((size_t)NN2*128*4);
  float*    score2 = (float*)alloc((size_t)NN2*4);
  unsigned* u2     = (unsigned*)alloc((size_t)NN2*4);
  int*      oldid2 = (int*)alloc((size_t)NN3*4);
  float*    scale2 = (float*)alloc((size_t)NN3*4);
  int*      ns3    = (int*)alloc((size_t)CAP3*4);
  int*      nd3    = (int*)alloc((size_t)CAP3*4);
  int*      rowptr3= (int*)alloc((size_t)NN3*4);
  int*      cursor3= (int*)alloc((size_t)NN3*4);
  int*      esrc3  = (int*)alloc((size_t)CAP3*4);
  float*    xp3    = (float*)alloc((size_t)NN3*256*4);
  float*    als3   = (float*)alloc((size_t)NN3*4);
  float*    ald3   = (float*)alloc((size_t)NN3*4);
  float*    out3   = (float*)alloc((size_t)NN3*256*4);
  float*    gatev  = (float*)alloc((size_t)NN3*4);
  float*    z1     = (float*)alloc((size_t)BG*512*4);
  float*    z2     = (float*)alloc((size_t)BG*128*4);
  if(off > ws_size) return;  // workspace too small: fail visibly

  auto cdiv = [](int a, int b){ return (a+b-1)/b; };

  hipMemsetAsync(base, 0, zend, stream);
  hipMemsetAsync(base + fstart, 0xFF, fend - fstart, stream);

  // ---------------- stage 1: GAT(3->32, H=2,F=16) ----------------
  k_xp1<<<cdiv(NB1,256),256,0,stream>>>(pos,W1,as1,ad1,xp1,als1,ald1);
  k_tile_count<<<256,1024,0,stream>>>(dst,cnt1);
  k_scan_g<<<BG,1024,0,stream>>>(cnt1,NPG1,EPG1,rowptr1,nullptr);
  k_tile_scatter<<<256,1024,0,stream>>>(src,dst,rowptr1,esrc1);
  k_gat_fused<2,16,768><<<NB1/32,256,0,stream>>>(xp1,als1,ald1,rowptr1,cnt1,esrc1,b1,out1,acc1,NPG1,NB1);
  k_inorm_score<32><<<cdiv(NB1*32,256),256,0,stream>>>(out1,acc1,p1,8192,NB1*32,score1,u1);
  // ---------------- pool 1 (k=2458) ----------------
  k_topk<<<BG,1024,0,stream>>>(u1,score1,8192,KP1,newid1,oldid1,scale1);
  k_edge_compact<<<BG*32,256,0,stream>>>(src,dst,nullptr,EPG1,32,EPG1,newid1,ecnt2,ns2,nd2,REG2,cnt2);
  // ---------------- stage 2: GAT(32->128, H=2,F=64) ----------------
  k_scan_g<<<BG,1024,0,stream>>>(cnt2,KP1,REG2,rowptr2,cursor2);
  k_scatter_r<<<CAP2/256,256,0,stream>>>(ns2,nd2,ecnt2,REG2,cursor2,esrc2);
  k_gemm_al<32,128,4,2><<<cdiv(NN2,8),256,0,stream>>>(out1,oldid1,scale1,W2,xp2,as2,ad2,als2,ald2,NN2);
  k_gat_fused<2,64,256><<<NN2/8,256,0,stream>>>(xp2,als2,ald2,rowptr2,cnt2,esrc2,b2,out2,acc2,KP1,NN2);
  k_inorm_score<128><<<cdiv(NN2*128,256),256,0,stream>>>(out2,acc2,p2,KP1,NN2*128,score2,u2);
  // ---------------- pool 2 (k=738) ----------------
  k_topk<<<BG,1024,0,stream>>>(u2,score2,KP1,KP2,newid2,oldid2,scale2);
  k_edge_compact<<<BG*4,256,0,stream>>>(ns2,nd2,ecnt2,0,4,REG2,newid2,ecnt3,ns3,nd3,REG3,cnt3);
  // ---------------- stage 3: GAT(128->256, H=1,F=256) ----------------
  k_scan_g<<<BG,1024,0,stream>>>(cnt3,KP2,REG3,rowptr3,cursor3);
  k_scatter_r<<<CAP3/256,256,0,stream>>>(ns3,nd3,ecnt3,REG3,cursor3,esrc3);
  k_gemm_al<128,256,4,1><<<cdiv(NN3,4),256,0,stream>>>(out2,oldid2,scale2,W3,xp3,as3,ad3,als3,ald3,NN3);
  k_gat_fused<1,256,128><<<NN3/4,256,0,stream>>>(xp3,als3,ald3,rowptr3,cnt3,esrc3,b3,out3,acc3,KP2,NN3);
  // ---------------- global attention + MLP head (stage-3 norm fused in) ----
  k_gate_fused<<<cdiv(NN3,4),256,0,stream>>>(out3,acc3,gw1,gb1,gw2,gb2,gatev,NN3);
  k_attn_gemm<<<dim3(cdiv(KP2,4),BG),256,0,stream>>>(out3,acc3,aw,ab,gatev,gvec);
  k_mlp_t<256,512,1><<<cdiv(BG*512,256),256,0,stream>>>(gvec,w1,bb1,z1,BG);
  k_mlp_t<512,128,1><<<cdiv(BG*128,256),256,0,stream>>>(z1,w2,bb2,z2,BG);
  k_head<<<BG,64,0,stream>>>(z2,w3,bb3,out);
}